// Round 14
// baseline (73.644 us; speedup 1.0000x reference)
//
#include <hip/hip_runtime.h>
#include <hip/hip_bf16.h>

// GlobalPoolDistance: RBF-kernel MMD over 3x3 patch unfolds (8,3,64,64) f32.
// N = 62*62 = 3844 patches, d = 27 (padded K=32). SIG2 = 0.2916.
// R14 = R12 with the manual asm-load/vmcnt protocol REMOVED (the isolated
// change): plain C++ loads everywhere; A-frags forced live by ONE empty
// asm "+v" tie (prevents the R8 sink/remat failure); B-stream scheduling
// left entirely to the compiler, which emits its own fine-grained counted
// vmcnt (m97 evidence) and can hoist the 16 unrolled B loads deeper than
// the manual 1-deep prefetch. R13's NaN root-caused: mixed asm-load +
// LDS-DMA + compiler-inserted waits make hand-counted vmcnt unsound --
// manual counting is only safe when I author EVERY VMEM op (R11/R13 both
// violated this). This round: correctness is compiler-owned.
// Recap: p-terms baked into MFMA pad cols (MFMA out IS the exp2 arg),
// split-bf16 3-MFMA gram, xx/yy triangle symmetry, 4 wave-jobs per block,
// unique-slot stores (no atomics), panel-major order, m204 XCD swizzle.
//
// ws: Ah|Al|Bh|Bl [16][3968][32] bf16 (4 x 4,063,232 B) + acc[32] f32
//     + part[24*1024] f32.  total ~16.35 MB.

#define NP    3844
#define NPAD  3968
#define KP    32

#define W_XY  7688     // 8 * 31 * 31  xy wave-jobs
#define W_ALL 15624    // + 2 * 8 * 496 tri wave-jobs
#define NBLK  3906     // W_ALL / 4 jobs per block

static constexpr float L_F   = 4.9475824173972215f;   // log2(e)/0.2916
static constexpr float C2L_F = 9.895164834794443f;    // 2*L

using bf16x8 = __attribute__((ext_vector_type(8))) short;
using f32x4  = __attribute__((ext_vector_type(4))) float;

#define MFMA16(a, b, c) __builtin_amdgcn_mfma_f32_16x16x32_bf16((a), (b), (c), 0, 0, 0)

__device__ inline unsigned short f2bf(float f) {
    union { float f; unsigned u; } v; v.f = f;
    unsigned r = v.u + 0x7FFFu + ((v.u >> 16) & 1u);   // RNE (no NaN inputs)
    return (unsigned short)(r >> 16);
}
__device__ inline float bf2f(unsigned short h) {
    union { unsigned u; float f; } v; v.u = ((unsigned)h) << 16;
    return v.f;
}
__device__ inline void pack_store(unsigned short* dst, const unsigned short* v) {
    uint4* d = (uint4*)dst;
#pragma unroll
    for (int q = 0; q < 4; ++q) {
        unsigned w0 = (unsigned)v[8 * q + 0] | ((unsigned)v[8 * q + 1] << 16);
        unsigned w1 = (unsigned)v[8 * q + 2] | ((unsigned)v[8 * q + 3] << 16);
        unsigned w2 = (unsigned)v[8 * q + 4] | ((unsigned)v[8 * q + 5] << 16);
        unsigned w3 = (unsigned)v[8 * q + 6] | ((unsigned)v[8 * q + 7] << 16);
        d[q] = make_uint4(w0, w1, w2, w3);
    }
}

// One thread per (im, patch). A-side scaled by 2L with p-cols; B-side plain.
__global__ __launch_bounds__(256) void gp_prep(const float* __restrict__ x,
                                               const float* __restrict__ y,
                                               unsigned short* __restrict__ Ah,
                                               unsigned short* __restrict__ Al,
                                               unsigned short* __restrict__ Bh,
                                               unsigned short* __restrict__ Bl) {
    int i = blockIdx.x * 256 + threadIdx.x;          // 16*NPAD = 63488
    if (i >= 16 * NPAD) return;
    int n = i % NPAD, im = i / NPAD;
    int b = im & 7;
    const float* src = (im >> 3) ? y : x;

    unsigned short hA[32], lA[32], hB[32], lB[32];
#pragma unroll
    for (int k = 0; k < 32; ++k) { hA[k] = 0; lA[k] = 0; hB[k] = 0; lB[k] = 0; }

    float sq = 0.0f;
    const bool valid = (n < NP);
    if (valid) {
        int r = n / 62, c = n % 62;
#pragma unroll
        for (int ch = 0; ch < 3; ++ch)
#pragma unroll
            for (int pr = 0; pr < 3; ++pr)
#pragma unroll
                for (int pc = 0; pc < 3; ++pc) {
                    int k = ch * 9 + pr * 3 + pc;
                    float v = src[(((b * 3 + ch) * 64) + r + pr) * 64 + (c + pc)];
                    unsigned short hb = f2bf(v);
                    hB[k] = hb; lB[k] = f2bf(v - bf2f(hb));
                    float sv = C2L_F * v;
                    unsigned short ha = f2bf(sv);
                    hA[k] = ha; lA[k] = f2bf(sv - bf2f(ha));
                    sq = fmaf(v, v, sq);
                }
    }
    // col 27: A = 2L (const), B = -sq/2 (pad: -1e30 -> exp2 -> 0)
    {
        unsigned short h = f2bf(C2L_F);
        hA[27] = h; lA[27] = f2bf(C2L_F - bf2f(h));
        float tb = valid ? -0.5f * sq : -1e30f;
        unsigned short hb = f2bf(tb);
        hB[27] = hb; lB[27] = f2bf(tb - bf2f(hb));
    }
    // col 28: A = -L*sq (pad: -1e30), B = 1
    {
        float pa = valid ? -L_F * sq : -1e30f;
        unsigned short ha = f2bf(pa);
        hA[28] = ha; lA[28] = f2bf(pa - bf2f(ha));
        hB[28] = f2bf(1.0f); lB[28] = 0;
    }

    pack_store(Ah + (size_t)i * KP, hA);
    pack_store(Al + (size_t)i * KP, lA);
    pack_store(Bh + (size_t)i * KP, hB);
    pack_store(Bl + (size_t)i * KP, lB);
}

// 4 independent rg-chains sharing one B fragment, then 16 exp2+add.
#define GROUP(AH0, AH1, AH2, AH3, AL0, AL1, AL2, AL3, BHC, BLC)              \
    do {                                                                     \
        f32x4 g0 = {0.f, 0.f, 0.f, 0.f}, g1 = {0.f, 0.f, 0.f, 0.f};          \
        f32x4 g2 = {0.f, 0.f, 0.f, 0.f}, g3 = {0.f, 0.f, 0.f, 0.f};          \
        g0 = MFMA16(AL0, BHC, g0); g1 = MFMA16(AL1, BHC, g1);                \
        g2 = MFMA16(AL2, BHC, g2); g3 = MFMA16(AL3, BHC, g3);                \
        g0 = MFMA16(AH0, BLC, g0); g1 = MFMA16(AH1, BLC, g1);                \
        g2 = MFMA16(AH2, BLC, g2); g3 = MFMA16(AH3, BLC, g3);                \
        g0 = MFMA16(AH0, BHC, g0); g1 = MFMA16(AH1, BHC, g1);                \
        g2 = MFMA16(AH2, BHC, g2); g3 = MFMA16(AH3, BHC, g3);                \
        s0 += __builtin_amdgcn_exp2f(g0[0]); s1 += __builtin_amdgcn_exp2f(g0[1]); \
        s2 += __builtin_amdgcn_exp2f(g0[2]); s3 += __builtin_amdgcn_exp2f(g0[3]); \
        s0 += __builtin_amdgcn_exp2f(g1[0]); s1 += __builtin_amdgcn_exp2f(g1[1]); \
        s2 += __builtin_amdgcn_exp2f(g1[2]); s3 += __builtin_amdgcn_exp2f(g1[3]); \
        s0 += __builtin_amdgcn_exp2f(g2[0]); s1 += __builtin_amdgcn_exp2f(g2[1]); \
        s2 += __builtin_amdgcn_exp2f(g2[2]); s3 += __builtin_amdgcn_exp2f(g2[3]); \
        s0 += __builtin_amdgcn_exp2f(g3[0]); s1 += __builtin_amdgcn_exp2f(g3[1]); \
        s2 += __builtin_amdgcn_exp2f(g3[2]); s3 += __builtin_amdgcn_exp2f(g3[3]); \
    } while (0)

// 4 wave-jobs per 256-thread block; no LDS, no barriers, no atomics, no
// manual waitcnts. (256,4): 128-VGPR cap.
__global__ __launch_bounds__(256, 4) void gp_pairs14(const unsigned short* __restrict__ Ah,
                                                     const unsigned short* __restrict__ Al,
                                                     const unsigned short* __restrict__ Bh,
                                                     const unsigned short* __restrict__ Bl,
                                                     float* __restrict__ part) {
    const int phys = blockIdx.x;
    const int xcd = phys & 7, oi = phys >> 3;
    // m204 bijective swizzle: 3906 = 8*488 + 2 (q=488, r=2)
    const int blk = (xcd < 2 ? xcd * 489 : 2 * 489 + (xcd - 2) * 488) + oi;

    const int t = threadIdx.x;
    const int wv = t >> 6, l = t & 63;
    const int l15 = l & 15, lhi = l >> 4;
    const int w = blk * 4 + wv;            // wave-job id, < 15624

    int type, b, bx, by, slot;
    float wt = 1.0f;
    if (w < W_XY) {
        type = 0; b = w / 961;
        int rr = w % 961; by = rr / 31; bx = rr % 31;
        slot = rr;
    } else {
        int v = w - W_XY;
        type = 1 + v / 3968;
        int r = v % 3968; b = r / 496; int t2 = r % 496;
        by = (int)((sqrtf(8.0f * (float)t2 + 1.0f) - 1.0f) * 0.5f);
        while ((by + 1) * (by + 2) / 2 <= t2) ++by;
        while (by * (by + 1) / 2 > t2) --by;
        bx = t2 - by * (by + 1) / 2;
        wt = (bx == by) ? 1.0f : 2.0f;
        slot = t2;
    }
    int imA, imB;
    if (type == 0)      { imA = b;     imB = 8 + b; }
    else if (type == 1) { imA = b;     imB = b;     }
    else                { imA = 8 + b; imB = 8 + b; }

    const size_t eA = ((size_t)(imA * NPAD + bx * 128 + l15)) * KP + lhi * 8;
    const size_t eB = ((size_t)(imB * NPAD + by * 128 + l15)) * KP + lhi * 8;
    const unsigned short* pAh = Ah + eA;
    const unsigned short* pAl = Al + eA;
    const unsigned short* pBh = Bh + eB;
    const unsigned short* pBl = Bl + eB;

    // A fragments: plain loads, then ONE empty-asm tie that (a) forces the
    // loads to complete here, (b) redefines the values so the compiler can
    // neither sink nor rematerialize them (the R8 failure mode).
    bf16x8 ah0 = *(const bf16x8*)(pAh),        ah1 = *(const bf16x8*)(pAh + 512);
    bf16x8 ah2 = *(const bf16x8*)(pAh + 1024), ah3 = *(const bf16x8*)(pAh + 1536);
    bf16x8 ah4 = *(const bf16x8*)(pAh + 2048), ah5 = *(const bf16x8*)(pAh + 2560);
    bf16x8 ah6 = *(const bf16x8*)(pAh + 3072), ah7 = *(const bf16x8*)(pAh + 3584);
    bf16x8 al0 = *(const bf16x8*)(pAl),        al1 = *(const bf16x8*)(pAl + 512);
    bf16x8 al2 = *(const bf16x8*)(pAl + 1024), al3 = *(const bf16x8*)(pAl + 1536);
    bf16x8 al4 = *(const bf16x8*)(pAl + 2048), al5 = *(const bf16x8*)(pAl + 2560);
    bf16x8 al6 = *(const bf16x8*)(pAl + 3072), al7 = *(const bf16x8*)(pAl + 3584);
    asm volatile(""
                 : "+v"(ah0), "+v"(ah1), "+v"(ah2), "+v"(ah3),
                   "+v"(ah4), "+v"(ah5), "+v"(ah6), "+v"(ah7),
                   "+v"(al0), "+v"(al1), "+v"(al2), "+v"(al3),
                   "+v"(al4), "+v"(al5), "+v"(al6), "+v"(al7));

    float s0 = 0.f, s1 = 0.f, s2 = 0.f, s3 = 0.f;

    // B stream: fully unrolled plain loads -- compiler hoists & inserts its
    // own counted vmcnt waits (m97-verified behavior).
#pragma unroll
    for (int cg = 0; cg < 8; ++cg) {
        const bf16x8 bhc = *(const bf16x8*)(pBh + cg * 512);
        const bf16x8 blc = *(const bf16x8*)(pBl + cg * 512);
        GROUP(ah0, ah1, ah2, ah3, al0, al1, al2, al3, bhc, blc);
        GROUP(ah4, ah5, ah6, ah7, al4, al5, al6, al7, bhc, blc);
    }

    float sacc = wt * ((s0 + s1) + (s2 + s3));

    // wave reduce, then ONE PLAIN STORE to a unique slot (no atomics)
#pragma unroll
    for (int o = 32; o > 0; o >>= 1) sacc += __shfl_down(sacc, o, 64);
    if (l == 0) part[(type * 8 + b) * 1024 + slot] = sacc;
}

// 24 blocks: block b sums its bucket's exact count of partials -> acc[b].
__global__ __launch_bounds__(256) void gp_reduce(const float* __restrict__ part,
                                                 float* __restrict__ acc) {
    const int bkt = blockIdx.x;
    const int cnt = (bkt < 8) ? 961 : 496;
    const float* p = part + bkt * 1024;
    float s = 0.0f;
    for (int i = threadIdx.x; i < cnt; i += 256) s += p[i];
#pragma unroll
    for (int o = 32; o > 0; o >>= 1) s += __shfl_down(s, o, 64);
    __shared__ float red[4];
    if ((threadIdx.x & 63) == 0) red[threadIdx.x >> 6] = s;
    __syncthreads();
    if (threadIdx.x == 0) acc[bkt] = (red[0] + red[1]) + (red[2] + red[3]);
}

__global__ void gp_final(const float* __restrict__ acc, float* __restrict__ out) {
    if (threadIdx.x == 0) {
        double s = 0.0;
        for (int b = 0; b < 8; ++b)
            s += -2.0 * (double)acc[b] + (double)acc[8 + b] + (double)acc[16 + b];
        out[0] = (float)(s / (8.0 * (double)NP * (double)NP));
    }
}

extern "C" void kernel_launch(void* const* d_in, const int* in_sizes, int n_in,
                              void* d_out, int out_size, void* d_ws, size_t ws_size,
                              hipStream_t stream) {
    const float* x = (const float*)d_in[0];
    const float* y = (const float*)d_in[1];
    const size_t MSZ = (size_t)16 * NPAD * KP;
    unsigned short* Ah = (unsigned short*)d_ws;
    unsigned short* Al = Ah + MSZ;
    unsigned short* Bh = Al + MSZ;
    unsigned short* Bl = Bh + MSZ;
    float* acc = (float*)(Bl + MSZ);
    float* part = acc + 32;

    gp_prep<<<(16 * NPAD) / 256, 256, 0, stream>>>(x, y, Ah, Al, Bh, Bl);
    gp_pairs14<<<NBLK, 256, 0, stream>>>(Ah, Al, Bh, Bl, part);
    gp_reduce<<<24, 256, 0, stream>>>(part, acc);
    gp_final<<<1, 1, 0, stream>>>(acc, (float*)d_out);
}

// Round 15
// 69.789 us; speedup vs baseline: 1.0552x; 1.0552x over previous
//
#include <hip/hip_runtime.h>
#include <hip/hip_bf16.h>

// GlobalPoolDistance: RBF-kernel MMD over 3x3 patch unfolds (8,3,64,64) f32.
// N = 62*62 = 3844 patches, d = 27 (padded K=32). SIG2 = 0.2916.
// R15 = R10 (best: 49.5us) with the B prefetch deepened 1 -> 3 pairs, all in
// REGISTERS (a B hi/lo pair = 8 VGPRs; 4 rotating pairs = 32 VGPRs; live set
// ~118). R14 arithmetic: per-job wall ~21k cyc vs 3.7k pipe work -> ~17k of
// memory waits = 8 cg steps x near-full loaded-L2 latency; 1-deep prefetch
// covered only ~450 cyc/step. 3-deep covers ~1400 cyc. Manual vmcnt stays
// SOUND: every VMEM op is my inline asm (R11 lesson: spills corrupt counts ->
// launch_bounds(64,3) = 170-VGPR cap, no spill; R13 lesson: never mix DMA/
// compiler VMEM into the counted stream). Protocol: prologue 16 A + 6 B
// loads, wait vmcnt(6) (A done, 3 pairs flying); k=0..4 issue pair k+3 then
// wait vmcnt(6); k=5,6,7 wait 4/2/0.
// Recap: p-terms baked into MFMA pad cols (MFMA out IS the exp2 arg),
// split-bf16 3-MFMA gram, xx/yy triangle symmetry, 1-wave jobs (no LDS, no
// barriers), unique-slot stores (no atomics), panel-major order, 8x1953
// bijective XCD swizzle.
//
// ws: Ah|Al|Bh|Bl [16][3968][32] bf16 (4 x 4,063,232 B) + acc[32] f32
//     + part[24*1024] f32.  total ~16.35 MB.

#define NP    3844
#define NPAD  3968
#define KP    32

#define W_XY  7688     // 8 * 31 * 31  xy wave-jobs
#define W_ALL 15624    // + 2 * 8 * 496 tri wave-jobs; 15624 = 8 * 1953
#define NBLK  15624

static constexpr float L_F   = 4.9475824173972215f;   // log2(e)/0.2916
static constexpr float C2L_F = 9.895164834794443f;    // 2*L

using bf16x8 = __attribute__((ext_vector_type(8))) short;
using f32x4  = __attribute__((ext_vector_type(4))) float;

#define MFMA16(a, b, c) __builtin_amdgcn_mfma_f32_16x16x32_bf16((a), (b), (c), 0, 0, 0)

__device__ inline unsigned short f2bf(float f) {
    union { float f; unsigned u; } v; v.f = f;
    unsigned r = v.u + 0x7FFFu + ((v.u >> 16) & 1u);   // RNE (no NaN inputs)
    return (unsigned short)(r >> 16);
}
__device__ inline float bf2f(unsigned short h) {
    union { unsigned u; float f; } v; v.u = ((unsigned)h) << 16;
    return v.f;
}
__device__ inline void pack_store(unsigned short* dst, const unsigned short* v) {
    uint4* d = (uint4*)dst;
#pragma unroll
    for (int q = 0; q < 4; ++q) {
        unsigned w0 = (unsigned)v[8 * q + 0] | ((unsigned)v[8 * q + 1] << 16);
        unsigned w1 = (unsigned)v[8 * q + 2] | ((unsigned)v[8 * q + 3] << 16);
        unsigned w2 = (unsigned)v[8 * q + 4] | ((unsigned)v[8 * q + 5] << 16);
        unsigned w3 = (unsigned)v[8 * q + 6] | ((unsigned)v[8 * q + 7] << 16);
        d[q] = make_uint4(w0, w1, w2, w3);
    }
}

// One thread per (im, patch). A-side scaled by 2L with p-cols; B-side plain.
__global__ __launch_bounds__(256) void gp_prep(const float* __restrict__ x,
                                               const float* __restrict__ y,
                                               unsigned short* __restrict__ Ah,
                                               unsigned short* __restrict__ Al,
                                               unsigned short* __restrict__ Bh,
                                               unsigned short* __restrict__ Bl) {
    int i = blockIdx.x * 256 + threadIdx.x;          // 16*NPAD = 63488
    if (i >= 16 * NPAD) return;
    int n = i % NPAD, im = i / NPAD;
    int b = im & 7;
    const float* src = (im >> 3) ? y : x;

    unsigned short hA[32], lA[32], hB[32], lB[32];
#pragma unroll
    for (int k = 0; k < 32; ++k) { hA[k] = 0; lA[k] = 0; hB[k] = 0; lB[k] = 0; }

    float sq = 0.0f;
    const bool valid = (n < NP);
    if (valid) {
        int r = n / 62, c = n % 62;
#pragma unroll
        for (int ch = 0; ch < 3; ++ch)
#pragma unroll
            for (int pr = 0; pr < 3; ++pr)
#pragma unroll
                for (int pc = 0; pc < 3; ++pc) {
                    int k = ch * 9 + pr * 3 + pc;
                    float v = src[(((b * 3 + ch) * 64) + r + pr) * 64 + (c + pc)];
                    unsigned short hb = f2bf(v);
                    hB[k] = hb; lB[k] = f2bf(v - bf2f(hb));
                    float sv = C2L_F * v;
                    unsigned short ha = f2bf(sv);
                    hA[k] = ha; lA[k] = f2bf(sv - bf2f(ha));
                    sq = fmaf(v, v, sq);
                }
    }
    // col 27: A = 2L (const), B = -sq/2 (pad: -1e30 -> exp2 -> 0)
    {
        unsigned short h = f2bf(C2L_F);
        hA[27] = h; lA[27] = f2bf(C2L_F - bf2f(h));
        float tb = valid ? -0.5f * sq : -1e30f;
        unsigned short hb = f2bf(tb);
        hB[27] = hb; lB[27] = f2bf(tb - bf2f(hb));
    }
    // col 28: A = -L*sq (pad: -1e30), B = 1
    {
        float pa = valid ? -L_F * sq : -1e30f;
        unsigned short ha = f2bf(pa);
        hA[28] = ha; lA[28] = f2bf(pa - bf2f(ha));
        hB[28] = f2bf(1.0f); lB[28] = 0;
    }

    pack_store(Ah + (size_t)i * KP, hA);
    pack_store(Al + (size_t)i * KP, lA);
    pack_store(Bh + (size_t)i * KP, hB);
    pack_store(Bl + (size_t)i * KP, lB);
}

// Opaque 16B global load with immediate offset: cannot be sunk or remat'd.
template<int OFF>
__device__ inline bf16x8 gload(const unsigned short* p) {
    bf16x8 r;
    asm volatile("global_load_dwordx4 %0, %1, off offset:%2"
                 : "=v"(r) : "v"(p), "i"(OFF));
    return r;
}

// 4 independent rg-chains sharing one B fragment, then 16 exp2+add.
#define GROUP(AH0, AH1, AH2, AH3, AL0, AL1, AL2, AL3, BHC, BLC)              \
    do {                                                                     \
        f32x4 g0 = {0.f, 0.f, 0.f, 0.f}, g1 = {0.f, 0.f, 0.f, 0.f};          \
        f32x4 g2 = {0.f, 0.f, 0.f, 0.f}, g3 = {0.f, 0.f, 0.f, 0.f};          \
        g0 = MFMA16(AL0, BHC, g0); g1 = MFMA16(AL1, BHC, g1);                \
        g2 = MFMA16(AL2, BHC, g2); g3 = MFMA16(AL3, BHC, g3);                \
        g0 = MFMA16(AH0, BLC, g0); g1 = MFMA16(AH1, BLC, g1);                \
        g2 = MFMA16(AH2, BLC, g2); g3 = MFMA16(AH3, BLC, g3);                \
        g0 = MFMA16(AH0, BHC, g0); g1 = MFMA16(AH1, BHC, g1);                \
        g2 = MFMA16(AH2, BHC, g2); g3 = MFMA16(AH3, BHC, g3);                \
        s0 += __builtin_amdgcn_exp2f(g0[0]); s1 += __builtin_amdgcn_exp2f(g0[1]); \
        s2 += __builtin_amdgcn_exp2f(g0[2]); s3 += __builtin_amdgcn_exp2f(g0[3]); \
        s0 += __builtin_amdgcn_exp2f(g1[0]); s1 += __builtin_amdgcn_exp2f(g1[1]); \
        s2 += __builtin_amdgcn_exp2f(g1[2]); s3 += __builtin_amdgcn_exp2f(g1[3]); \
        s0 += __builtin_amdgcn_exp2f(g2[0]); s1 += __builtin_amdgcn_exp2f(g2[1]); \
        s2 += __builtin_amdgcn_exp2f(g2[2]); s3 += __builtin_amdgcn_exp2f(g2[3]); \
        s0 += __builtin_amdgcn_exp2f(g3[0]); s1 += __builtin_amdgcn_exp2f(g3[1]); \
        s2 += __builtin_amdgcn_exp2f(g3[2]); s3 += __builtin_amdgcn_exp2f(g3[3]); \
    } while (0)

#define BOTH(BHC, BLC)                                                       \
    do {                                                                     \
        GROUP(ah0, ah1, ah2, ah3, al0, al1, al2, al3, BHC, BLC);             \
        GROUP(ah4, ah5, ah6, ah7, al4, al5, al6, al7, BHC, BLC);             \
    } while (0)

// steady-state step: issue pair k+3 into (NH,NL), wait vmcnt(6) -> (CH,CL)
// ready, compute.
#define STEP6(CH, CL, NH, NL, PH, PL, OFFN)                                  \
    do {                                                                     \
        NH = gload<OFFN>(PH); NL = gload<OFFN>(PL);                          \
        asm volatile("s_waitcnt vmcnt(6)" : "+v"(CH), "+v"(CL));             \
        __builtin_amdgcn_sched_barrier(0);                                   \
        BOTH(CH, CL);                                                        \
    } while (0)

#define STEPN(N, CH, CL)                                                     \
    do {                                                                     \
        asm volatile("s_waitcnt vmcnt(" #N ")" : "+v"(CH), "+v"(CL));        \
        __builtin_amdgcn_sched_barrier(0);                                   \
        BOTH(CH, CL);                                                        \
    } while (0)

// One 128x128 tile per wave (64-thr block). 3-deep register B prefetch.
// (64,3): 170-VGPR cap -> ~118 live set fits with NO spills (spill VMEM
// would corrupt the counted-vmcnt protocol -- the R11 failure mode).
__global__ __launch_bounds__(64, 3) void gp_pairs15(const unsigned short* __restrict__ Ah,
                                                    const unsigned short* __restrict__ Al,
                                                    const unsigned short* __restrict__ Bh,
                                                    const unsigned short* __restrict__ Bl,
                                                    float* __restrict__ part) {
    const int phys = blockIdx.x;
    const int w = (phys & 7) * 1953 + (phys >> 3);   // bijective, 15624 = 8*1953

    const int l = threadIdx.x & 63;
    const int l15 = l & 15, lhi = l >> 4;

    int type, b, bx, by, slot;
    float wt = 1.0f;
    if (w < W_XY) {
        type = 0; b = w / 961;
        int rr = w % 961; by = rr / 31; bx = rr % 31;
        slot = rr;
    } else {
        int v = w - W_XY;
        type = 1 + v / 3968;
        int r = v % 3968; b = r / 496; int t2 = r % 496;
        by = (int)((sqrtf(8.0f * (float)t2 + 1.0f) - 1.0f) * 0.5f);
        while ((by + 1) * (by + 2) / 2 <= t2) ++by;
        while (by * (by + 1) / 2 > t2) --by;
        bx = t2 - by * (by + 1) / 2;
        wt = (bx == by) ? 1.0f : 2.0f;
        slot = t2;
    }
    int imA, imB;
    if (type == 0)      { imA = b;     imB = 8 + b; }
    else if (type == 1) { imA = b;     imB = b;     }
    else                { imA = 8 + b; imB = 8 + b; }

    // base pointers (cg 0-3 via imm offset 0..3072; cg 4-7 via +4096B base)
    const size_t eA = ((size_t)(imA * NPAD + bx * 128 + l15)) * KP + lhi * 8;
    const size_t eB = ((size_t)(imB * NPAD + by * 128 + l15)) * KP + lhi * 8;
    const unsigned short* pAh0 = Ah + eA;
    const unsigned short* pAl0 = Al + eA;
    const unsigned short* pAh4 = pAh0 + 2048;
    const unsigned short* pAl4 = pAl0 + 2048;
    const unsigned short* pBh0 = Bh + eB;
    const unsigned short* pBl0 = Bl + eB;
    const unsigned short* pBh4 = pBh0 + 2048;
    const unsigned short* pBl4 = pBl0 + 2048;

    // A fragments: 16 opaque loads, pinned for the whole job (64 VGPR).
    bf16x8 ah0 = gload<0>(pAh0),    ah1 = gload<1024>(pAh0);
    bf16x8 ah2 = gload<2048>(pAh0), ah3 = gload<3072>(pAh0);
    bf16x8 ah4 = gload<0>(pAh4),    ah5 = gload<1024>(pAh4);
    bf16x8 ah6 = gload<2048>(pAh4), ah7 = gload<3072>(pAh4);
    bf16x8 al0 = gload<0>(pAl0),    al1 = gload<1024>(pAl0);
    bf16x8 al2 = gload<2048>(pAl0), al3 = gload<3072>(pAl0);
    bf16x8 al4 = gload<0>(pAl4),    al5 = gload<1024>(pAl4);
    bf16x8 al6 = gload<2048>(pAl4), al7 = gload<3072>(pAl4);

    // 3 B pairs in flight before the A-wait (cg0, cg1, cg2)
    bf16x8 uh = gload<0>(pBh0),    ul = gload<0>(pBl0);
    bf16x8 vh = gload<1024>(pBh0), vl = gload<1024>(pBl0);
    bf16x8 wh = gload<2048>(pBh0), wl = gload<2048>(pBl0);
    bf16x8 zh, zl;

    // wait A (16 oldest drain; 6 B loads stay outstanding), pin all 16 A regs
    asm volatile("s_waitcnt vmcnt(6)"
                 : "+v"(ah0), "+v"(ah1), "+v"(ah2), "+v"(ah3),
                   "+v"(ah4), "+v"(ah5), "+v"(ah6), "+v"(ah7),
                   "+v"(al0), "+v"(al1), "+v"(al2), "+v"(al3),
                   "+v"(al4), "+v"(al5), "+v"(al6), "+v"(al7));
    __builtin_amdgcn_sched_barrier(0);

    float s0 = 0.f, s1 = 0.f, s2 = 0.f, s3 = 0.f;

    // k=0..4: issue pair k+3, wait vmcnt(6) (pair k ready); k=5..7 drain.
    STEP6(uh, ul, zh, zl, pBh0, pBl0, 3072);   // k=0: use cg0, issue cg3
    STEP6(vh, vl, uh, ul, pBh4, pBl4, 0);      // k=1: use cg1, issue cg4
    STEP6(wh, wl, vh, vl, pBh4, pBl4, 1024);   // k=2: use cg2, issue cg5
    STEP6(zh, zl, wh, wl, pBh4, pBl4, 2048);   // k=3: use cg3, issue cg6
    STEP6(uh, ul, zh, zl, pBh4, pBl4, 3072);   // k=4: use cg4, issue cg7
    STEPN(4, vh, vl);                          // k=5: use cg5
    STEPN(2, wh, wl);                          // k=6: use cg6
    STEPN(0, zh, zl);                          // k=7: use cg7

    float sacc = wt * ((s0 + s1) + (s2 + s3));

    // wave reduce, then ONE PLAIN STORE to a unique slot (no atomics)
#pragma unroll
    for (int o = 32; o > 0; o >>= 1) sacc += __shfl_down(sacc, o, 64);
    if (l == 0) part[(type * 8 + b) * 1024 + slot] = sacc;
}

// 24 blocks: block b sums its bucket's exact count of partials -> acc[b].
__global__ __launch_bounds__(256) void gp_reduce(const float* __restrict__ part,
                                                 float* __restrict__ acc) {
    const int bkt = blockIdx.x;
    const int cnt = (bkt < 8) ? 961 : 496;
    const float* p = part + bkt * 1024;
    float s = 0.0f;
    for (int i = threadIdx.x; i < cnt; i += 256) s += p[i];
#pragma unroll
    for (int o = 32; o > 0; o >>= 1) s += __shfl_down(s, o, 64);
    __shared__ float red[4];
    if ((threadIdx.x & 63) == 0) red[threadIdx.x >> 6] = s;
    __syncthreads();
    if (threadIdx.x == 0) acc[bkt] = (red[0] + red[1]) + (red[2] + red[3]);
}

__global__ void gp_final(const float* __restrict__ acc, float* __restrict__ out) {
    if (threadIdx.x == 0) {
        double s = 0.0;
        for (int b = 0; b < 8; ++b)
            s += -2.0 * (double)acc[b] + (double)acc[8 + b] + (double)acc[16 + b];
        out[0] = (float)(s / (8.0 * (double)NP * (double)NP));
    }
}

extern "C" void kernel_launch(void* const* d_in, const int* in_sizes, int n_in,
                              void* d_out, int out_size, void* d_ws, size_t ws_size,
                              hipStream_t stream) {
    const float* x = (const float*)d_in[0];
    const float* y = (const float*)d_in[1];
    const size_t MSZ = (size_t)16 * NPAD * KP;
    unsigned short* Ah = (unsigned short*)d_ws;
    unsigned short* Al = Ah + MSZ;
    unsigned short* Bh = Al + MSZ;
    unsigned short* Bl = Bh + MSZ;
    float* acc = (float*)(Bl + MSZ);
    float* part = acc + 32;

    gp_prep<<<(16 * NPAD) / 256, 256, 0, stream>>>(x, y, Ah, Al, Bh, Bl);
    gp_pairs15<<<NBLK, 64, 0, stream>>>(Ah, Al, Bh, Bl, part);
    gp_reduce<<<24, 256, 0, stream>>>(part, acc);
    gp_final<<<1, 1, 0, stream>>>(acc, (float*)d_out);
}